// Round 3
// baseline (1339.408 us; speedup 1.0000x reference)
//
#include <hip/hip_runtime.h>
#include <hip/hip_bf16.h>
#include <cstdint>
#include <cstddef>

#define MAX_K 70
#define LCAP 128
#define BN_EPS 1e-5f

// ---------------- load/store helpers (f32 or bf16 storage) ----------------
__device__ inline float loadv(const float* p, size_t i) { return p[i]; }
__device__ inline float loadv(const __hip_bfloat16* p, size_t i) {
    return __bfloat162float(p[i]);
}
__device__ inline void storev(float* p, size_t i, float v) { p[i] = v; }
__device__ inline void storev(__hip_bfloat16* p, size_t i, float v) {
    p[i] = __float2bfloat16(v);
}

// ---------------------------------------------------------------- utilities
__global__ void zero_kernel(float* __restrict__ p, size_t n) {
    size_t i = (size_t)blockIdx.x * blockDim.x + threadIdx.x;
    size_t stride = (size_t)gridDim.x * blockDim.x;
    for (; i < n; i += stride) p[i] = 0.f;
}

// ------------------------------------------------------ stage 1a: histogram
__global__ void hist_kernel(const int* __restrict__ ccids,
                            int* __restrict__ cnt, int N) {
    int i = blockIdx.x * blockDim.x + threadIdx.x;
    int stride = gridDim.x * blockDim.x;
    for (; i < N; i += stride) atomicAdd(&cnt[ccids[i]], 1);
}

// --------------------------------------- stage 1b: exclusive scan over cnt
// block = 256 threads x 8 elems = 2048 per block
__global__ __launch_bounds__(256) void scan_partial(const int* __restrict__ cnt,
                                                    int* __restrict__ bsum, int C) {
    __shared__ int sc[256];
    int b = blockIdx.x, tid = threadIdx.x;
    int base = b * 2048 + tid * 8;
    int t = 0;
    #pragma unroll
    for (int e = 0; e < 8; ++e) {
        int c = base + e;
        t += (c < C) ? cnt[c] : 0;
    }
    sc[tid] = t;
    __syncthreads();
    for (int o = 128; o > 0; o >>= 1) {
        if (tid < o) sc[tid] += sc[tid + o];
        __syncthreads();
    }
    if (tid == 0) bsum[b] = sc[0];
}

__global__ void scan_tops(int* __restrict__ bsum, int nb) {
    if (blockIdx.x == 0 && threadIdx.x == 0) {
        int run = 0;
        for (int k = 0; k < nb; ++k) { int t = bsum[k]; bsum[k] = run; run += t; }
    }
}

__global__ __launch_bounds__(256) void scan_final(const int* __restrict__ cnt,
                                                  const int* __restrict__ btop,
                                                  int* __restrict__ off,
                                                  int* __restrict__ woff, int C) {
    __shared__ int sc[256];
    int b = blockIdx.x, tid = threadIdx.x;
    int base = b * 2048 + tid * 8;
    int v[8];
    int tsum = 0;
    #pragma unroll
    for (int e = 0; e < 8; ++e) {
        int c = base + e;
        v[e] = (c < C) ? cnt[c] : 0;
        tsum += v[e];
    }
    sc[tid] = tsum;
    __syncthreads();
    for (int d = 1; d < 256; d <<= 1) {
        int t = (tid >= d) ? sc[tid - d] : 0;
        __syncthreads();
        sc[tid] += t;
        __syncthreads();
    }
    int run = btop[b] + sc[tid] - tsum;  // exclusive prefix for this thread
    #pragma unroll
    for (int e = 0; e < 8; ++e) {
        int c = base + e;
        if (c < C) { off[c] = run; woff[c] = run; }
        run += v[e];
    }
}

// ------------------------------------ stage 1c: compact counting-sort scatter
__global__ void scatter2_kernel(const int* __restrict__ ccids,
                                int* __restrict__ woff,
                                int* __restrict__ sorted, int N) {
    int i = blockIdx.x * blockDim.x + threadIdx.x;
    int stride = gridDim.x * blockDim.x;
    for (; i < N; i += stride) {
        int c = ccids[i];
        int p = atomicAdd(&woff[c], 1);
        sorted[p] = i;
    }
}

// ------------------- stage 1d+2a: rank, pack, layer-1 GEMM (350 -> 32)
// one wave per component, 4 components per block
__global__ __launch_bounds__(256) void layer1_kernel(
    const float* __restrict__ feat, const int* __restrict__ cnt,
    const int* __restrict__ off, const int* __restrict__ sorted,
    const float* __restrict__ W1, const float* __restrict__ b1,
    float* __restrict__ z1, int C) {
    __shared__ int   sidx[4][LCAP];
    __shared__ float xtile[4][MAX_K * 5];
    int w    = threadIdx.x >> 6;
    int lane = threadIdx.x & 63;
    int comp = blockIdx.x * 4 + w;
    int len = 0, base = 0;
    if (comp < C) { len = cnt[comp]; base = off[comp]; }
    bool small = (len <= LCAP);
    if (small) {
        for (int e = lane; e < len; e += 64) sidx[w][e] = sorted[base + e];
    }
    __syncthreads();
    // deterministic rank = number of member indices smaller than mine
    for (int e = lane; e < len; e += 64) {
        int my = small ? sidx[w][e] : sorted[base + e];
        int r = 0;
        if (small) {
            for (int j = 0; j < len; ++j) r += (sidx[w][j] < my) ? 1 : 0;
        } else {  // never taken for this data; correctness fallback
            for (int j = 0; j < len; ++j) r += (sorted[base + j] < my) ? 1 : 0;
        }
        if (r < MAX_K) {
            #pragma unroll
            for (int k = 0; k < 5; ++k)
                xtile[w][r * 5 + k] = feat[(size_t)my * 5 + k];
        }
    }
    __syncthreads();
    // ranks are a permutation: xtile[0 .. min(len,70)*5) is densely written
    if (comp < C && lane < 32) {
        float acc = b1[lane];
        int kmax = min(len, MAX_K) * 5;
        for (int t = 0; t < kmax; ++t)
            acc = fmaf(xtile[w][t], W1[t * 32 + lane], acc);
        z1[(size_t)comp * 32 + lane] = acc;
    }
}

// --------------------------------------- per-channel sum / sumsq reduction
template <typename T, int FO>
__global__ __launch_bounds__(256) void reduce_kernel(
    const T* __restrict__ z, double* __restrict__ dsum,
    double* __restrict__ dsq, int C) {
    size_t n = (size_t)C * FO;
    size_t i = (size_t)blockIdx.x * 256 + threadIdx.x;
    size_t stride = (size_t)gridDim.x * 256;  // multiple of FO -> fixed channel
    double s = 0.0, s2 = 0.0;
    for (; i < n; i += stride) {
        double v = (double)loadv(z, i);
        s += v; s2 += v * v;
    }
    __shared__ double ss[256], ssq[256];
    int tid = threadIdx.x;
    ss[tid] = s; ssq[tid] = s2;
    __syncthreads();
    for (int off = (256 / FO) >> 1; off > 0; off >>= 1) {
        if (tid < off * FO) {
            ss[tid]  += ss[tid + off * FO];
            ssq[tid] += ssq[tid + off * FO];
        }
        __syncthreads();
    }
    if (tid < FO) {
        unsafeAtomicAdd(&dsum[tid], ss[tid]);
        unsafeAtomicAdd(&dsq[tid],  ssq[tid]);
    }
}

// ------------------------------- fold BN stats into per-channel scale/shift
template <int FO>
__global__ void finalize_kernel(const double* __restrict__ dsum,
                                const double* __restrict__ dsq,
                                const float* __restrict__ g,
                                const float* __restrict__ be,
                                float* __restrict__ aS, float* __restrict__ cS,
                                int C) {
    int ch = threadIdx.x;
    if (ch < FO) {
        double m = dsum[ch] / (double)C;
        double v = dsq[ch] / (double)C - m * m;
        float rs = rsqrtf((float)v + BN_EPS);
        float a = g[ch] * rs;
        aS[ch] = a;
        cS[ch] = be[ch] - (float)m * a;
    }
}

// ---- generic layer: zout = relu(aS*zin+cS) @ W + b, with fused BN stats ----
template <typename TI, typename TO, int FI, int FO, int CT, int RT>
__global__ __launch_bounds__(256) void layer_kernel(
    const TI* __restrict__ zin, const float* __restrict__ W,
    const float* __restrict__ bias, const float* __restrict__ aS,
    const float* __restrict__ cS, TO* __restrict__ zout,
    double* __restrict__ dsum, double* __restrict__ dsq, int C) {
    constexpr int CHG  = FO / CT;    // channel groups
    constexpr int NSUB = 256 / CHG;  // row groups
    constexpr int R    = NSUB * RT;  // rows per block
    __shared__ float h[R][FI + 1];
    __shared__ float sps[NSUB * FO];
    __shared__ float spq[NSUB * FO];
    int tid = threadIdx.x;
    int c0 = blockIdx.x * R;
    for (int t = tid; t < R * FI; t += 256) {
        int r = t / FI, k = t % FI;
        int c = c0 + r;
        float v = (c < C) ? loadv(zin, (size_t)c * FI + k) : 0.f;
        h[r][k] = fmaxf(fmaf(aS[k], v, cS[k]), 0.f);
    }
    __syncthreads();
    int cg  = tid % CHG;
    int sub = tid / CHG;
    int chbase = cg * CT;
    float acc[RT][CT];
    #pragma unroll
    for (int i = 0; i < RT; ++i)
        #pragma unroll
        for (int j = 0; j < CT; ++j) acc[i][j] = 0.f;
    for (int k = 0; k < FI; ++k) {
        float wv[CT];
        #pragma unroll
        for (int j4 = 0; j4 < CT; j4 += 4) {
            const float4 wq = *reinterpret_cast<const float4*>(
                &W[(size_t)k * FO + chbase + j4]);
            wv[j4 + 0] = wq.x; wv[j4 + 1] = wq.y;
            wv[j4 + 2] = wq.z; wv[j4 + 3] = wq.w;
        }
        #pragma unroll
        for (int i = 0; i < RT; ++i) {
            float hv = h[sub * RT + i][k];
            #pragma unroll
            for (int j = 0; j < CT; ++j) acc[i][j] = fmaf(hv, wv[j], acc[i][j]);
        }
    }
    // epilogue: store z and accumulate per-channel sum/sumsq partials
    float ps[CT], pq[CT];
    #pragma unroll
    for (int j = 0; j < CT; ++j) { ps[j] = 0.f; pq[j] = 0.f; }
    #pragma unroll
    for (int i = 0; i < RT; ++i) {
        int c = c0 + sub * RT + i;
        if (c < C) {
            #pragma unroll
            for (int j = 0; j < CT; ++j) {
                float z = acc[i][j] + bias[chbase + j];
                storev(zout, (size_t)c * FO + chbase + j, z);
                ps[j] += z;
                pq[j] += z * z;
            }
        }
    }
    #pragma unroll
    for (int j = 0; j < CT; ++j) {
        sps[sub * FO + chbase + j] = ps[j];
        spq[sub * FO + chbase + j] = pq[j];
    }
    __syncthreads();
    if (tid < FO) {
        float s = 0.f, q = 0.f;
        #pragma unroll
        for (int s2 = 0; s2 < NSUB; ++s2) {
            s += sps[s2 * FO + tid];
            q += spq[s2 * FO + tid];
        }
        unsafeAtomicAdd(&dsum[tid], (double)s);
        unsafeAtomicAdd(&dsq[tid],  (double)q);
    }
}

// ----------------------------------------------- per-image component counts
__global__ void imgcnt_kernel(const int* __restrict__ imgid,
                              int* __restrict__ pcnt, int C, int B) {
    __shared__ int scnt[64];
    int tid = threadIdx.x;
    if (tid < B) scnt[tid] = 0;
    __syncthreads();
    for (int i = blockIdx.x * 256 + tid; i < C; i += gridDim.x * 256)
        atomicAdd(&scnt[imgid[i]], 1);
    __syncthreads();
    if (tid < B) atomicAdd(&pcnt[tid], scnt[tid]);
}

// ------------- segment-sum of relu(bn4(z4)) into pool[B,256] (LDS accum)
__global__ __launch_bounds__(256) void pool_kernel(
    const __hip_bfloat16* __restrict__ z4, const int* __restrict__ imgid,
    const float* __restrict__ aS, const float* __restrict__ cS,
    float* __restrict__ pool, int C, int B) {
    __shared__ float spool[64 * 256];  // exactly 64 KiB
    int tid = threadIdx.x;
    int nb = B * 256;
    for (int t = tid; t < nb; t += 256) spool[t] = 0.f;
    __syncthreads();
    float a = aS[tid], cc = cS[tid];
    int per  = (C + gridDim.x - 1) / gridDim.x;
    int cbeg = blockIdx.x * per;
    int cend = min(cbeg + per, C);
    for (int c = cbeg; c < cend; ++c) {
        int img = imgid[c];
        float v = loadv(z4, (size_t)c * 256 + tid);
        float hv = fmaxf(fmaf(a, v, cc), 0.f);
        spool[img * 256 + tid] += hv;  // thread owns its (img,ch) this iter
    }
    __syncthreads();
    int start = ((int)blockIdx.x * 2048) % nb;  // stagger atomic contention
    for (int t0 = 0; t0 < nb; t0 += 256) {
        int t = (start + t0 + tid) % nb;
        unsafeAtomicAdd(&pool[t], spool[t]);
    }
}

// ------------------------------ mean over comps, BN over the 64 image rows
__global__ void bn5_kernel(const float* __restrict__ pool,
                           const int* __restrict__ pcnt,
                           const float* __restrict__ g5,
                           const float* __restrict__ be5,
                           float* __restrict__ y, int B) {
    int ch = threadIdx.x;  // 256 channels
    double s = 0.0, s2 = 0.0;
    for (int b = 0; b < B; ++b) {
        float c = (float)pcnt[b]; if (c < 1.f) c = 1.f;
        float v = pool[b * 256 + ch] / c;
        s += (double)v; s2 += (double)v * (double)v;
    }
    double m = s / (double)B;
    double var = s2 / (double)B - m * m;
    float rs = rsqrtf((float)var + BN_EPS);
    float a = g5[ch] * rs;
    float cc = be5[ch] - (float)m * a;
    for (int b = 0; b < B; ++b) {
        float c = (float)pcnt[b]; if (c < 1.f) c = 1.f;
        float v = pool[b * 256 + ch] / c;
        y[b * 256 + ch] = fmaf(a, v, cc);
    }
}

// ------------------------------------------------------- final FC + ReLU
__global__ __launch_bounds__(256) void fc_kernel(
    const float* __restrict__ y, const float* __restrict__ Wfc,
    const float* __restrict__ bfc, float* __restrict__ out, int NC) {
    int b = blockIdx.y;
    int ch = blockIdx.x * 256 + threadIdx.x;
    __shared__ float sy[256];
    sy[threadIdx.x] = y[b * 256 + threadIdx.x];
    __syncthreads();
    if (ch < NC) {
        float acc = bfc[ch];
        for (int k = 0; k < 256; ++k)
            acc = fmaf(sy[k], Wfc[(size_t)k * NC + ch], acc);
        out[(size_t)b * NC + ch] = fmaxf(acc, 0.f);
    }
}

// ---------------------------------------------------------------- launcher
extern "C" void kernel_launch(void* const* d_in, const int* in_sizes, int n_in,
                              void* d_out, int out_size, void* d_ws,
                              size_t ws_size, hipStream_t stream) {
    const float* item_feat = (const float*)d_in[0];
    const int*   ccids     = (const int*)d_in[1];
    const int*   imgid     = (const int*)d_in[2];
    const float* W1  = (const float*)d_in[3];
    const float* b1  = (const float*)d_in[4];
    const float* g1  = (const float*)d_in[5];
    const float* be1 = (const float*)d_in[6];
    const float* W2  = (const float*)d_in[7];
    const float* b2  = (const float*)d_in[8];
    const float* g2  = (const float*)d_in[9];
    const float* be2 = (const float*)d_in[10];
    const float* W3  = (const float*)d_in[11];
    const float* b3  = (const float*)d_in[12];
    const float* g3  = (const float*)d_in[13];
    const float* be3 = (const float*)d_in[14];
    const float* W4  = (const float*)d_in[15];
    const float* b4  = (const float*)d_in[16];
    const float* g4  = (const float*)d_in[17];
    const float* be4 = (const float*)d_in[18];
    const float* g5  = (const float*)d_in[19];
    const float* be5 = (const float*)d_in[20];
    const float* Wfc = (const float*)d_in[21];
    const float* bfc = (const float*)d_in[22];
    float* out = (float*)d_out;

    const int N  = in_sizes[1];        // 4,000,000 items
    const int C  = in_sizes[2];        // 200,000 components
    const int NC = in_sizes[22];       // 1000 classes
    const int B  = out_size / NC;      // 64 images

    // ---- workspace layout: explicit liveness-based aliasing ----
    uint8_t* ws = (uint8_t*)d_ws;
    size_t off_ = 0;
    auto alloc = [&](size_t bytes) -> void* {
        void* p = (void*)(ws + off_);
        off_ += (bytes + 255) & ~(size_t)255;
        return p;
    };
    int*    cnt    = (int*)alloc((size_t)C * 4);
    double* dstats = (double*)alloc((size_t)(32 + 64 + 128 + 256) * 2 * 8);
    float*  pool   = (float*)alloc((size_t)B * 256 * 4);
    int*    pcnt   = (int*)alloc((size_t)B * 4);
    size_t zeroBytes = off_;  // accumulated-into region -> zero every call
    float*  scales = (float*)alloc((size_t)(32 + 64 + 128 + 256) * 2 * 4);
    float*  y      = (float*)alloc((size_t)B * 256 * 4);
    int*    off    = (int*)alloc((size_t)C * 4);
    int*    woff   = (int*)alloc((size_t)C * 4);
    int*    bsum   = (int*)alloc((size_t)1024 * 4);
    void* regionA = alloc((size_t)C * 128 * 2);   // 51.2 MB: z1 f32 -> z3 bf16
    void* regionB = alloc((size_t)C * 256 * 2);   // 102.4 MB: sorted -> z2 -> z4
    (void)ws_size;  // total ~157 MB

    float*           z1     = (float*)regionA;            // C x 32 f32
    __hip_bfloat16*  z3     = (__hip_bfloat16*)regionA;   // C x 128 bf16
    int*             sorted = (int*)regionB;              // N int (dies @L1)
    float*           z2     = (float*)regionB;            // C x 64 f32 (dies @L3)
    __hip_bfloat16*  z4     = (__hip_bfloat16*)regionB;   // C x 256 bf16

    double *ds1 = dstats +   0, *dq1 = dstats +  32;
    double *ds2 = dstats +  64, *dq2 = dstats + 128;
    double *ds3 = dstats + 192, *dq3 = dstats + 320;
    double *ds4 = dstats + 448, *dq4 = dstats + 704;
    float *aS1 = scales +   0, *cS1 = scales +  32;
    float *aS2 = scales +  64, *cS2 = scales + 128;
    float *aS3 = scales + 192, *cS3 = scales + 320;
    float *aS4 = scales + 448, *cS4 = scales + 704;

    const int nb = (C + 2047) / 2048;  // scan blocks

    zero_kernel<<<256, 256, 0, stream>>>((float*)ws, zeroBytes / 4);
    hist_kernel<<<4096, 256, 0, stream>>>(ccids, cnt, N);
    imgcnt_kernel<<<256, 256, 0, stream>>>(imgid, pcnt, C, B);
    scan_partial<<<nb, 256, 0, stream>>>(cnt, bsum, C);
    scan_tops<<<1, 64, 0, stream>>>(bsum, nb);
    scan_final<<<nb, 256, 0, stream>>>(cnt, bsum, off, woff, C);
    scatter2_kernel<<<4096, 256, 0, stream>>>(ccids, woff, sorted, N);

    layer1_kernel<<<(C + 3) / 4, 256, 0, stream>>>(item_feat, cnt, off, sorted,
                                                   W1, b1, z1, C);
    reduce_kernel<float, 32><<<512, 256, 0, stream>>>(z1, ds1, dq1, C);
    finalize_kernel<32><<<1, 32, 0, stream>>>(ds1, dq1, g1, be1, aS1, cS1, C);

    layer_kernel<float, float, 32, 64, 4, 8>
        <<<(C + 127) / 128, 256, 0, stream>>>(z1, W2, b2, aS1, cS1, z2, ds2, dq2, C);
    finalize_kernel<64><<<1, 64, 0, stream>>>(ds2, dq2, g2, be2, aS2, cS2, C);

    layer_kernel<float, __hip_bfloat16, 64, 128, 4, 8>
        <<<(C + 63) / 64, 256, 0, stream>>>(z2, W3, b3, aS2, cS2, z3, ds3, dq3, C);
    finalize_kernel<128><<<1, 128, 0, stream>>>(ds3, dq3, g3, be3, aS3, cS3, C);

    layer_kernel<__hip_bfloat16, __hip_bfloat16, 128, 256, 8, 8>
        <<<(C + 63) / 64, 256, 0, stream>>>(z3, W4, b4, aS3, cS3, z4, ds4, dq4, C);
    finalize_kernel<256><<<1, 256, 0, stream>>>(ds4, dq4, g4, be4, aS4, cS4, C);

    pool_kernel<<<512, 256, 0, stream>>>(z4, imgid, aS4, cS4, pool, C, B);
    bn5_kernel<<<1, 256, 0, stream>>>(pool, pcnt, g5, be5, y, B);

    dim3 fcg((NC + 255) / 256, B);
    fc_kernel<<<fcg, 256, 0, stream>>>(y, Wfc, bfc, out, NC);
}

// Round 4
// 1130.422 us; speedup vs baseline: 1.1849x; 1.1849x over previous
//
#include <hip/hip_runtime.h>
#include <hip/hip_bf16.h>
#include <cstdint>
#include <cstddef>

#define MAX_K 70
#define LCAP 128
#define BN_EPS 1e-5f

// ---------------- load/store helpers (f32 or bf16 storage) ----------------
__device__ inline float loadv(const float* p, size_t i) { return p[i]; }
__device__ inline float loadv(const __hip_bfloat16* p, size_t i) {
    return __bfloat162float(p[i]);
}
__device__ inline void storev(float* p, size_t i, float v) { p[i] = v; }
__device__ inline void storev(__hip_bfloat16* p, size_t i, float v) {
    p[i] = __float2bfloat16(v);
}

// ---------------------------------------------------------------- utilities
__global__ void zero_kernel(float* __restrict__ p, size_t n) {
    size_t i = (size_t)blockIdx.x * blockDim.x + threadIdx.x;
    size_t stride = (size_t)gridDim.x * blockDim.x;
    for (; i < n; i += stride) p[i] = 0.f;
}

// ------------------------------------------------------ stage 1a: histogram
__global__ void hist_kernel(const int* __restrict__ ccids,
                            int* __restrict__ cnt, int N) {
    int i = blockIdx.x * blockDim.x + threadIdx.x;
    int stride = gridDim.x * blockDim.x;
    for (; i < N; i += stride) atomicAdd(&cnt[ccids[i]], 1);
}

// --------------------------------------- stage 1b: exclusive scan over cnt
// block = 256 threads x 8 elems = 2048 per block
__global__ __launch_bounds__(256) void scan_partial(const int* __restrict__ cnt,
                                                    int* __restrict__ bsum, int C) {
    __shared__ int sc[256];
    int b = blockIdx.x, tid = threadIdx.x;
    int base = b * 2048 + tid * 8;
    int t = 0;
    #pragma unroll
    for (int e = 0; e < 8; ++e) {
        int c = base + e;
        t += (c < C) ? cnt[c] : 0;
    }
    sc[tid] = t;
    __syncthreads();
    for (int o = 128; o > 0; o >>= 1) {
        if (tid < o) sc[tid] += sc[tid + o];
        __syncthreads();
    }
    if (tid == 0) bsum[b] = sc[0];
}

__global__ void scan_tops(int* __restrict__ bsum, int nb) {
    if (blockIdx.x == 0 && threadIdx.x == 0) {
        int run = 0;
        for (int k = 0; k < nb; ++k) { int t = bsum[k]; bsum[k] = run; run += t; }
    }
}

__global__ __launch_bounds__(256) void scan_final(const int* __restrict__ cnt,
                                                  const int* __restrict__ btop,
                                                  int* __restrict__ off,
                                                  int* __restrict__ woff, int C) {
    __shared__ int sc[256];
    int b = blockIdx.x, tid = threadIdx.x;
    int base = b * 2048 + tid * 8;
    int v[8];
    int tsum = 0;
    #pragma unroll
    for (int e = 0; e < 8; ++e) {
        int c = base + e;
        v[e] = (c < C) ? cnt[c] : 0;
        tsum += v[e];
    }
    sc[tid] = tsum;
    __syncthreads();
    for (int d = 1; d < 256; d <<= 1) {
        int t = (tid >= d) ? sc[tid - d] : 0;
        __syncthreads();
        sc[tid] += t;
        __syncthreads();
    }
    int run = btop[b] + sc[tid] - tsum;  // exclusive prefix for this thread
    #pragma unroll
    for (int e = 0; e < 8; ++e) {
        int c = base + e;
        if (c < C) { off[c] = run; woff[c] = run; }
        run += v[e];
    }
}

// --------------- stage 1c: XCD-partitioned counting-sort scatter
// group g = blockIdx & 7 (round-robin -> same XCD); group g handles comps
// [g*cg, (g+1)*cg) so each XCD's L2 owns a contiguous slice of `sorted`:
// destination lines accumulate all their writes in ONE L2 -> 1 writeback/line.
__global__ __launch_bounds__(256) void scatter2_kernel(
    const int4* __restrict__ ccids4, int* __restrict__ woff,
    int* __restrict__ sorted, int n4, int cg) {
    int g   = blockIdx.x & 7;
    int k   = blockIdx.x >> 3;
    int nk  = gridDim.x >> 3;
    int clo = g * cg, chi = clo + cg;
    for (int q = k * 256 + threadIdx.x; q < n4; q += nk * 256) {
        int4 v = ccids4[q];
        int base = q * 4;
        #pragma unroll
        for (int e = 0; e < 4; ++e) {
            int c = (e == 0) ? v.x : (e == 1) ? v.y : (e == 2) ? v.z : v.w;
            if (c >= clo && c < chi) {
                int p = atomicAdd(&woff[c], 1);
                sorted[p] = base + e;
            }
        }
    }
}

// ------------------- stage 1d+2a: rank, pack, layer-1 GEMM (350 -> 32)
// one wave per component, 4 components per block
__global__ __launch_bounds__(256) void layer1_kernel(
    const float* __restrict__ feat, const int* __restrict__ cnt,
    const int* __restrict__ off, const int* __restrict__ sorted,
    const float* __restrict__ W1, const float* __restrict__ b1,
    float* __restrict__ z1, int C) {
    __shared__ int   sidx[4][LCAP];
    __shared__ float xtile[4][MAX_K * 5];
    int w    = threadIdx.x >> 6;
    int lane = threadIdx.x & 63;
    int comp = blockIdx.x * 4 + w;
    int len = 0, base = 0;
    if (comp < C) { len = cnt[comp]; base = off[comp]; }
    bool small = (len <= LCAP);
    if (small) {
        for (int e = lane; e < len; e += 64) sidx[w][e] = sorted[base + e];
    }
    __syncthreads();
    // deterministic rank = number of member indices smaller than mine
    for (int e = lane; e < len; e += 64) {
        int my = small ? sidx[w][e] : sorted[base + e];
        int r = 0;
        if (small) {
            for (int j = 0; j < len; ++j) r += (sidx[w][j] < my) ? 1 : 0;
        } else {  // never taken for this data; correctness fallback
            for (int j = 0; j < len; ++j) r += (sorted[base + j] < my) ? 1 : 0;
        }
        if (r < MAX_K) {
            #pragma unroll
            for (int k = 0; k < 5; ++k)
                xtile[w][r * 5 + k] = feat[(size_t)my * 5 + k];
        }
    }
    __syncthreads();
    // ranks are a permutation: xtile[0 .. min(len,70)*5) is densely written
    if (comp < C && lane < 32) {
        float acc = b1[lane];
        int kmax = min(len, MAX_K) * 5;
        for (int t = 0; t < kmax; ++t)
            acc = fmaf(xtile[w][t], W1[t * 32 + lane], acc);
        z1[(size_t)comp * 32 + lane] = acc;
    }
}

// --------------------------------------- per-channel sum / sumsq reduction
template <typename T, int FO>
__global__ __launch_bounds__(256) void reduce_kernel(
    const T* __restrict__ z, double* __restrict__ dsum,
    double* __restrict__ dsq, int C) {
    size_t n = (size_t)C * FO;
    size_t i = (size_t)blockIdx.x * 256 + threadIdx.x;
    size_t stride = (size_t)gridDim.x * 256;  // multiple of FO -> fixed channel
    double s = 0.0, s2 = 0.0;
    for (; i < n; i += stride) {
        double v = (double)loadv(z, i);
        s += v; s2 += v * v;
    }
    __shared__ double ss[256], ssq[256];
    int tid = threadIdx.x;
    ss[tid] = s; ssq[tid] = s2;
    __syncthreads();
    for (int off = (256 / FO) >> 1; off > 0; off >>= 1) {
        if (tid < off * FO) {
            ss[tid]  += ss[tid + off * FO];
            ssq[tid] += ssq[tid + off * FO];
        }
        __syncthreads();
    }
    if (tid < FO) {
        unsafeAtomicAdd(&dsum[tid], ss[tid]);
        unsafeAtomicAdd(&dsq[tid],  ssq[tid]);
    }
}

// ------------------------------- fold BN stats into per-channel scale/shift
template <int FO>
__global__ void finalize_kernel(const double* __restrict__ dsum,
                                const double* __restrict__ dsq,
                                const float* __restrict__ g,
                                const float* __restrict__ be,
                                float* __restrict__ aS, float* __restrict__ cS,
                                int C) {
    int ch = threadIdx.x;
    if (ch < FO) {
        double m = dsum[ch] / (double)C;
        double v = dsq[ch] / (double)C - m * m;
        float rs = rsqrtf((float)v + BN_EPS);
        float a = g[ch] * rs;
        aS[ch] = a;
        cS[ch] = be[ch] - (float)m * a;
    }
}

// ---- generic layer: zout = relu(aS*zin+cS) @ W + b, with fused BN stats ----
template <typename TI, typename TO, int FI, int FO, int CT, int RT>
__global__ __launch_bounds__(256) void layer_kernel(
    const TI* __restrict__ zin, const float* __restrict__ W,
    const float* __restrict__ bias, const float* __restrict__ aS,
    const float* __restrict__ cS, TO* __restrict__ zout,
    double* __restrict__ dsum, double* __restrict__ dsq, int C) {
    constexpr int CHG  = FO / CT;    // channel groups
    constexpr int NSUB = 256 / CHG;  // row groups
    constexpr int R    = NSUB * RT;  // rows per block
    __shared__ float h[R][FI + 1];
    __shared__ float sps[NSUB * FO];
    __shared__ float spq[NSUB * FO];
    int tid = threadIdx.x;
    int c0 = blockIdx.x * R;
    for (int t = tid; t < R * FI; t += 256) {
        int r = t / FI, k = t % FI;
        int c = c0 + r;
        float v = (c < C) ? loadv(zin, (size_t)c * FI + k) : 0.f;
        h[r][k] = fmaxf(fmaf(aS[k], v, cS[k]), 0.f);
    }
    __syncthreads();
    int cg  = tid % CHG;
    int sub = tid / CHG;
    int chbase = cg * CT;
    float acc[RT][CT];
    #pragma unroll
    for (int i = 0; i < RT; ++i)
        #pragma unroll
        for (int j = 0; j < CT; ++j) acc[i][j] = 0.f;
    for (int k = 0; k < FI; ++k) {
        float wv[CT];
        #pragma unroll
        for (int j4 = 0; j4 < CT; j4 += 4) {
            const float4 wq = *reinterpret_cast<const float4*>(
                &W[(size_t)k * FO + chbase + j4]);
            wv[j4 + 0] = wq.x; wv[j4 + 1] = wq.y;
            wv[j4 + 2] = wq.z; wv[j4 + 3] = wq.w;
        }
        #pragma unroll
        for (int i = 0; i < RT; ++i) {
            float hv = h[sub * RT + i][k];
            #pragma unroll
            for (int j = 0; j < CT; ++j) acc[i][j] = fmaf(hv, wv[j], acc[i][j]);
        }
    }
    // epilogue: store z and accumulate per-channel sum/sumsq partials
    float ps[CT], pq[CT];
    #pragma unroll
    for (int j = 0; j < CT; ++j) { ps[j] = 0.f; pq[j] = 0.f; }
    #pragma unroll
    for (int i = 0; i < RT; ++i) {
        int c = c0 + sub * RT + i;
        if (c < C) {
            #pragma unroll
            for (int j = 0; j < CT; ++j) {
                float z = acc[i][j] + bias[chbase + j];
                storev(zout, (size_t)c * FO + chbase + j, z);
                ps[j] += z;
                pq[j] += z * z;
            }
        }
    }
    #pragma unroll
    for (int j = 0; j < CT; ++j) {
        sps[sub * FO + chbase + j] = ps[j];
        spq[sub * FO + chbase + j] = pq[j];
    }
    __syncthreads();
    if (tid < FO) {
        float s = 0.f, q = 0.f;
        #pragma unroll
        for (int s2 = 0; s2 < NSUB; ++s2) {
            s += sps[s2 * FO + tid];
            q += spq[s2 * FO + tid];
        }
        unsafeAtomicAdd(&dsum[tid], (double)s);
        unsafeAtomicAdd(&dsq[tid],  (double)q);
    }
}

// ----------------------------------------------- per-image component counts
__global__ void imgcnt_kernel(const int* __restrict__ imgid,
                              int* __restrict__ pcnt, int C, int B) {
    __shared__ int scnt[64];
    int tid = threadIdx.x;
    if (tid < B) scnt[tid] = 0;
    __syncthreads();
    for (int i = blockIdx.x * 256 + tid; i < C; i += gridDim.x * 256)
        atomicAdd(&scnt[imgid[i]], 1);
    __syncthreads();
    if (tid < B) atomicAdd(&pcnt[tid], scnt[tid]);
}

// ------------- segment-sum of relu(bn4(z4)) into pool[B,256] (LDS accum)
__global__ __launch_bounds__(256) void pool_kernel(
    const __hip_bfloat16* __restrict__ z4, const int* __restrict__ imgid,
    const float* __restrict__ aS, const float* __restrict__ cS,
    float* __restrict__ pool, int C, int B) {
    __shared__ float spool[64 * 256];  // exactly 64 KiB
    int tid = threadIdx.x;
    int nb = B * 256;
    for (int t = tid; t < nb; t += 256) spool[t] = 0.f;
    __syncthreads();
    float a = aS[tid], cc = cS[tid];
    int per  = (C + gridDim.x - 1) / gridDim.x;
    int cbeg = blockIdx.x * per;
    int cend = min(cbeg + per, C);
    for (int c = cbeg; c < cend; ++c) {
        int img = imgid[c];
        float v = loadv(z4, (size_t)c * 256 + tid);
        float hv = fmaxf(fmaf(a, v, cc), 0.f);
        spool[img * 256 + tid] += hv;  // thread owns its (img,ch) this iter
    }
    __syncthreads();
    int start = ((int)blockIdx.x * 2048) % nb;  // stagger atomic contention
    for (int t0 = 0; t0 < nb; t0 += 256) {
        int t = (start + t0 + tid) % nb;
        unsafeAtomicAdd(&pool[t], spool[t]);
    }
}

// ------------------------------ mean over comps, BN over the 64 image rows
__global__ void bn5_kernel(const float* __restrict__ pool,
                           const int* __restrict__ pcnt,
                           const float* __restrict__ g5,
                           const float* __restrict__ be5,
                           float* __restrict__ y, int B) {
    int ch = threadIdx.x;  // 256 channels
    double s = 0.0, s2 = 0.0;
    for (int b = 0; b < B; ++b) {
        float c = (float)pcnt[b]; if (c < 1.f) c = 1.f;
        float v = pool[b * 256 + ch] / c;
        s += (double)v; s2 += (double)v * (double)v;
    }
    double m = s / (double)B;
    double var = s2 / (double)B - m * m;
    float rs = rsqrtf((float)var + BN_EPS);
    float a = g5[ch] * rs;
    float cc = be5[ch] - (float)m * a;
    for (int b = 0; b < B; ++b) {
        float c = (float)pcnt[b]; if (c < 1.f) c = 1.f;
        float v = pool[b * 256 + ch] / c;
        y[b * 256 + ch] = fmaf(a, v, cc);
    }
}

// ------------------------------------------------------- final FC + ReLU
__global__ __launch_bounds__(256) void fc_kernel(
    const float* __restrict__ y, const float* __restrict__ Wfc,
    const float* __restrict__ bfc, float* __restrict__ out, int NC) {
    int b = blockIdx.y;
    int ch = blockIdx.x * 256 + threadIdx.x;
    __shared__ float sy[256];
    sy[threadIdx.x] = y[b * 256 + threadIdx.x];
    __syncthreads();
    if (ch < NC) {
        float acc = bfc[ch];
        for (int k = 0; k < 256; ++k)
            acc = fmaf(sy[k], Wfc[(size_t)k * NC + ch], acc);
        out[(size_t)b * NC + ch] = fmaxf(acc, 0.f);
    }
}

// ---------------------------------------------------------------- launcher
extern "C" void kernel_launch(void* const* d_in, const int* in_sizes, int n_in,
                              void* d_out, int out_size, void* d_ws,
                              size_t ws_size, hipStream_t stream) {
    const float* item_feat = (const float*)d_in[0];
    const int*   ccids     = (const int*)d_in[1];
    const int*   imgid     = (const int*)d_in[2];
    const float* W1  = (const float*)d_in[3];
    const float* b1  = (const float*)d_in[4];
    const float* g1  = (const float*)d_in[5];
    const float* be1 = (const float*)d_in[6];
    const float* W2  = (const float*)d_in[7];
    const float* b2  = (const float*)d_in[8];
    const float* g2  = (const float*)d_in[9];
    const float* be2 = (const float*)d_in[10];
    const float* W3  = (const float*)d_in[11];
    const float* b3  = (const float*)d_in[12];
    const float* g3  = (const float*)d_in[13];
    const float* be3 = (const float*)d_in[14];
    const float* W4  = (const float*)d_in[15];
    const float* b4  = (const float*)d_in[16];
    const float* g4  = (const float*)d_in[17];
    const float* be4 = (const float*)d_in[18];
    const float* g5  = (const float*)d_in[19];
    const float* be5 = (const float*)d_in[20];
    const float* Wfc = (const float*)d_in[21];
    const float* bfc = (const float*)d_in[22];
    float* out = (float*)d_out;

    const int N  = in_sizes[1];        // 4,000,000 items
    const int C  = in_sizes[2];        // 200,000 components
    const int NC = in_sizes[22];       // 1000 classes
    const int B  = out_size / NC;      // 64 images

    // ---- workspace layout: explicit liveness-based aliasing ----
    uint8_t* ws = (uint8_t*)d_ws;
    size_t off_ = 0;
    auto alloc = [&](size_t bytes) -> void* {
        void* p = (void*)(ws + off_);
        off_ += (bytes + 255) & ~(size_t)255;
        return p;
    };
    int*    cnt    = (int*)alloc((size_t)C * 4);
    double* dstats = (double*)alloc((size_t)(32 + 64 + 128 + 256) * 2 * 8);
    float*  pool   = (float*)alloc((size_t)B * 256 * 4);
    int*    pcnt   = (int*)alloc((size_t)B * 4);
    size_t zeroBytes = off_;  // accumulated-into region -> zero every call
    float*  scales = (float*)alloc((size_t)(32 + 64 + 128 + 256) * 2 * 4);
    float*  y      = (float*)alloc((size_t)B * 256 * 4);
    int*    off    = (int*)alloc((size_t)C * 4);
    int*    woff   = (int*)alloc((size_t)C * 4);
    int*    bsum   = (int*)alloc((size_t)1024 * 4);
    void* regionA = alloc((size_t)C * 128 * 2);   // 51.2 MB: z1 f32 -> z3 bf16
    void* regionB = alloc((size_t)C * 256 * 2);   // 102.4 MB: sorted -> z2 -> z4
    (void)ws_size;  // total ~157 MB

    float*           z1     = (float*)regionA;            // C x 32 f32
    __hip_bfloat16*  z3     = (__hip_bfloat16*)regionA;   // C x 128 bf16
    int*             sorted = (int*)regionB;              // N int (dies @L1)
    float*           z2     = (float*)regionB;            // C x 64 f32 (dies @L3)
    __hip_bfloat16*  z4     = (__hip_bfloat16*)regionB;   // C x 256 bf16

    double *ds1 = dstats +   0, *dq1 = dstats +  32;
    double *ds2 = dstats +  64, *dq2 = dstats + 128;
    double *ds3 = dstats + 192, *dq3 = dstats + 320;
    double *ds4 = dstats + 448, *dq4 = dstats + 704;
    float *aS1 = scales +   0, *cS1 = scales +  32;
    float *aS2 = scales +  64, *cS2 = scales + 128;
    float *aS3 = scales + 192, *cS3 = scales + 320;
    float *aS4 = scales + 448, *cS4 = scales + 704;

    const int nb = (C + 2047) / 2048;  // scan blocks
    const int cg = (C + 7) / 8;        // comps per XCD group

    zero_kernel<<<256, 256, 0, stream>>>((float*)ws, zeroBytes / 4);
    hist_kernel<<<4096, 256, 0, stream>>>(ccids, cnt, N);
    imgcnt_kernel<<<256, 256, 0, stream>>>(imgid, pcnt, C, B);
    scan_partial<<<nb, 256, 0, stream>>>(cnt, bsum, C);
    scan_tops<<<1, 64, 0, stream>>>(bsum, nb);
    scan_final<<<nb, 256, 0, stream>>>(cnt, bsum, off, woff, C);
    scatter2_kernel<<<2048, 256, 0, stream>>>((const int4*)ccids, woff, sorted,
                                              N / 4, cg);

    layer1_kernel<<<(C + 3) / 4, 256, 0, stream>>>(item_feat, cnt, off, sorted,
                                                   W1, b1, z1, C);
    reduce_kernel<float, 32><<<512, 256, 0, stream>>>(z1, ds1, dq1, C);
    finalize_kernel<32><<<1, 32, 0, stream>>>(ds1, dq1, g1, be1, aS1, cS1, C);

    layer_kernel<float, float, 32, 64, 4, 8>
        <<<(C + 127) / 128, 256, 0, stream>>>(z1, W2, b2, aS1, cS1, z2, ds2, dq2, C);
    finalize_kernel<64><<<1, 64, 0, stream>>>(ds2, dq2, g2, be2, aS2, cS2, C);

    layer_kernel<float, __hip_bfloat16, 64, 128, 4, 8>
        <<<(C + 63) / 64, 256, 0, stream>>>(z2, W3, b3, aS2, cS2, z3, ds3, dq3, C);
    finalize_kernel<128><<<1, 128, 0, stream>>>(ds3, dq3, g3, be3, aS3, cS3, C);

    layer_kernel<__hip_bfloat16, __hip_bfloat16, 128, 256, 8, 8>
        <<<(C + 63) / 64, 256, 0, stream>>>(z3, W4, b4, aS3, cS3, z4, ds4, dq4, C);
    finalize_kernel<256><<<1, 256, 0, stream>>>(ds4, dq4, g4, be4, aS4, cS4, C);

    pool_kernel<<<512, 256, 0, stream>>>(z4, imgid, aS4, cS4, pool, C, B);
    bn5_kernel<<<1, 256, 0, stream>>>(pool, pcnt, g5, be5, y, B);

    dim3 fcg((NC + 255) / 256, B);
    fc_kernel<<<fcg, 256, 0, stream>>>(y, Wfc, bfc, out, NC);
}